// Round 10
// baseline (336.454 us; speedup 1.0000x reference)
//
#include <hip/hip_runtime.h>
#include <hip/hip_bf16.h>
#include <stdint.h>

// Problem constants (fixed by setup_inputs)
constexpr int Bn  = 8;
constexpr int Cc  = 512;
constexpr int ICc = 256;
constexpr int HWc = 48 * 48;           // 2304
constexpr float BN_EPS = 1e-5f;

typedef unsigned short u16;
typedef __attribute__((ext_vector_type(8))) short short8;   // 8 bf16 (4 VGPRs)
typedef __attribute__((ext_vector_type(4))) float f32x4;    // MFMA C/D frag

__device__ __forceinline__ u16 f2bf(float f) {
    uint32_t u = __builtin_bit_cast(uint32_t, f);
    u += 0x7fffu + ((u >> 16) & 1u);     // RNE
    return (u16)(u >> 16);
}
__device__ __forceinline__ float bf2f(u16 h) {
    uint32_t u = ((uint32_t)h) << 16;
    return __builtin_bit_cast(float, u);
}
// async global->LDS, 16B per lane; lds dst is wave-uniform base (HW adds lane*16)
__device__ __forceinline__ void load_lds16(const void* g, void* l) {
    __builtin_amdgcn_global_load_lds(
        (const __attribute__((address_space(1))) void*)(uintptr_t)g,
        (__attribute__((address_space(3))) void*)(uintptr_t)l, 16, 0, 0);
}
template <int N> __device__ __forceinline__ void wait_vmcnt() {
    if constexpr (N == 0)       asm volatile("s_waitcnt vmcnt(0)" ::: "memory");
    else if constexpr (N == 3)  asm volatile("s_waitcnt vmcnt(3)" ::: "memory");
    else if constexpr (N == 4)  asm volatile("s_waitcnt vmcnt(4)" ::: "memory");
    else if constexpr (N == 6)  asm volatile("s_waitcnt vmcnt(6)" ::: "memory");
    else if constexpr (N == 8)  asm volatile("s_waitcnt vmcnt(8)" ::: "memory");
    else if constexpr (N == 9)  asm volatile("s_waitcnt vmcnt(9)" ::: "memory");
    else if constexpr (N == 12) asm volatile("s_waitcnt vmcnt(12)" ::: "memory");
}
__device__ __forceinline__ void wait_lgkm0() {
    asm volatile("s_waitcnt lgkmcnt(0)" ::: "memory");
}
__device__ __forceinline__ void barrier_fenced() {
    __builtin_amdgcn_s_barrier();
    asm volatile("" ::: "memory");      // keep LDS reads below the barrier
}
// float atomic max via the two-branch int/uint trick; init bits = 0xFFFFFFFF
// (NaN) are replaced by ANY real value in both branches.
__device__ __forceinline__ void atomicMaxF(float* addr, float v) {
    if (v >= 0.f) atomicMax((int*)addr, __float_as_int(v));
    else          atomicMin((unsigned int*)addr, __float_as_uint(v));
}

// ---------------------------------------------------------------------------
// Front cast: thph_w bf16 (rows 0..255=th_w, 256..511=ph_w), g_w bf16,
// bias_thph fp32 [th_b | ph_b].
// ---------------------------------------------------------------------------
__global__ __launch_bounds__(256)
void cast_front(const float* __restrict__ th_w, const float* __restrict__ ph_w,
                const float* __restrict__ g_w, const float* __restrict__ th_b,
                const float* __restrict__ ph_b, u16* __restrict__ wcat,
                float* __restrict__ bias_thph) {
    int idx = blockIdx.x * 256 + threadIdx.x;
    if (idx < 98304) {                           // ushort4 casts
        const float4* src;
        if (idx < 32768)       src = (const float4*)th_w + idx;
        else if (idx < 65536)  src = (const float4*)ph_w + (idx - 32768);
        else                   src = (const float4*)g_w  + (idx - 65536);
        float4 v = *src;
        ushort4 o;
        o.x = f2bf(v.x); o.y = f2bf(v.y); o.z = f2bf(v.z); o.w = f2bf(v.w);
        ((ushort4*)wcat)[idx] = o;
    } else if (idx < 98816) {                    // 512 bias floats
        int i = idx - 98304;
        bias_thph[i] = (i < 256) ? th_b[i] : ph_b[i - 256];
    }
}

__global__ __launch_bounds__(256)
void cast_w(const float* __restrict__ a, u16* __restrict__ out) {
    int idx = blockIdx.x * 256 + threadIdx.x;    // 0..32767
    float4 v = ((const float4*)a)[idx];
    ushort4 o;
    o.x = f2bf(v.x); o.y = f2bf(v.y); o.z = f2bf(v.z); o.w = f2bf(v.w);
    ((ushort4*)out)[idx] = o;
}

// ---------------------------------------------------------------------------
// x (B,C,HW) fp32 -> xt (B,HW,C) bf16, 64c x 32p LDS-tiled, ushort2 stores
// ---------------------------------------------------------------------------
__global__ __launch_bounds__(256)
void transpose_cast_x(const float* __restrict__ x, u16* __restrict__ xt) {
    __shared__ float t[64][33];
    const int b = blockIdx.z;
    const int p0 = blockIdx.x * 32;     // HW dir
    const int c0 = blockIdx.y * 64;     // C dir
    const int tx = threadIdx.x & 31, ty = threadIdx.x >> 5;   // ty 0..7
    const float* xb = x + (size_t)b * Cc * HWc;
#pragma unroll
    for (int r = 0; r < 8; ++r)
        t[r * 8 + ty][tx] = xb[(size_t)(c0 + r * 8 + ty) * HWc + p0 + tx];
    __syncthreads();
    u16* xtb = xt + (size_t)b * HWc * Cc;
    const int cc = (threadIdx.x & 31) * 2, pp = threadIdx.x >> 5;
#pragma unroll
    for (int r = 0; r < 4; ++r) {
        int p = r * 8 + pp;
        ushort2 v;
        v.x = f2bf(t[cc][p]);
        v.y = f2bf(t[cc + 1][p]);
        *(ushort2*)&xtb[(size_t)(p0 + p) * Cc + c0 + cc] = v;
    }
}

// ---------------------------------------------------------------------------
// bf16 MFMA GEMM: C[m][n] = sum_k A[m][k] * B[n][k] (+ bias)
//   TM=128: 128x128 tile, wave 2x2 (64x64).  TM=64: 64x128, wave 2x2 (32x64).
// Pipelined staging with counted vmcnt; NBUF chosen so LDS stays 48KB =
// 3 blocks/CU (round-7/8 verified): TM=128 NBUF=3, TM=64 NBUF=4.
// LDS chunk-XOR swizzle (T2, rule 21): bank conflicts 3.98M -> 0 (round-1).
//
// SMODE (softmax fusion, round-9):
//   0: plain.
//   1: S-gemm — epilogue publishes per-row max over this block's 128 cols
//      via atomicMaxF into s0g[bz*HWc + row] (buffer pre-set to 0xFF bits).
//   2: PV — A holds RAW scores; after each LDS->reg A-frag read, apply
//      e = exp(s - m_row) in-register (m_row loaded once per lane; A-row of
//      lane = wm+i*16+m16), repack bf16, accumulate l_row. Epilogue reduces
//      l over the 4 quad-lanes (k-partition), broadcasts via LDS, stores
//      y = acc/l. Eliminates the softmax_rows kernel and its 170MB stream.
// STORE==0: bf16 C; STORE==1: fp32 C. STATS: fused per-channel(m) sum/sumsq.
// bias_mode: 0 none, 1 per-n, 2 per-m.
// ---------------------------------------------------------------------------
template <int TM, int STORE, bool STATS, int SMODE = 0>
__global__ __launch_bounds__(256, 2)
void mfma_gemm(const u16* __restrict__ A, const u16* __restrict__ B,
               void* __restrict__ Cout, const float* __restrict__ bias,
               int bias_mode, int K, int ldA, int ldB, int ldC,
               size_t sA, size_t sB, size_t sC,
               float* __restrict__ s0g, float* __restrict__ s1g) {
    constexpr int MI    = TM / 32;               // 4 (TM=128) or 2 (TM=64)
    constexpr int LPS   = (TM == 128) ? 4 : 3;   // global_load_lds per wave/stage
    constexpr int NBUF  = (TM == 128) ? 3 : 4;   // keeps LDS at 48KB either way
    constexpr int DEPTH = NBUF - 1;
    __shared__ __align__(16) u16 As[NBUF][TM * 32];
    __shared__ __align__(16) u16 Bs[NBUF][128 * 32];
    __shared__ float lsl[TM];                    // SMODE2 row-sum broadcast
    const int bz = blockIdx.z;
    const int m0 = blockIdx.y * TM, n0 = blockIdx.x * 128;
    const u16* Ab = A + (size_t)bz * sA + (size_t)m0 * ldA;
    const u16* Bb = B + (size_t)bz * sB + (size_t)n0 * ldB;
    const int tid = threadIdx.x, lane = tid & 63, w = tid >> 6;
    const int wm = (w & 1) * (TM / 2);
    const int wn = (w >> 1) * 64;
    const int quad = lane >> 4, m16 = lane & 15;

    f32x4 acc[MI][4];
#pragma unroll
    for (int i = 0; i < MI; ++i)
#pragma unroll
        for (int j = 0; j < 4; ++j) acc[i][j] = (f32x4){0.f, 0.f, 0.f, 0.f};

    // SMODE2 state: row max (from S-gemm atomics) + running exp-sum.
    float mq[MI], ls[MI];
    if constexpr (SMODE == 2) {
#pragma unroll
        for (int i = 0; i < MI; ++i) {
            mq[i] = s0g[(size_t)bz * HWc + m0 + wm + i * 16 + m16];
            ls[i] = 0.f;
        }
    }

    // staging: linear slot L -> row = L>>2; SOURCE chunk = (L&3)^((L>>3)&3)
    const int L0 = 2 * w * 64 + lane, L1 = L0 + 64;
    const int br0 = L0 >> 2, bc0 = ((L0 & 3) ^ ((L0 >> 3) & 3)) * 8;
    const int br1 = L1 >> 2, bc1 = ((L1 & 3) ^ ((L1 >> 3) & 3)) * 8;
    const int ar0 = (TM == 128) ? br0 : (tid >> 2);
    const int ac0 = (TM == 128) ? bc0 : (((tid & 3) ^ ((tid >> 3) & 3)) * 8);

    auto stage = [&](int buf, int k0) {
        if (TM == 128) {
            load_lds16(Ab + (size_t)ar0 * ldA + k0 + ac0, &As[buf][2 * w * 512]);
            load_lds16(Ab + (size_t)br1 * ldA + k0 + bc1, &As[buf][(2 * w + 1) * 512]);
        } else {
            load_lds16(Ab + (size_t)ar0 * ldA + k0 + ac0, &As[buf][w * 512]);
        }
        load_lds16(Bb + (size_t)br0 * ldB + k0 + bc0, &Bs[buf][2 * w * 512]);
        load_lds16(Bb + (size_t)br1 * ldB + k0 + bc1, &Bs[buf][(2 * w + 1) * 512]);
    };

    // swizzled read: chunk quad of row r is at slot quad ^ ((r>>1)&3)
    const int sq = (quad ^ ((m16 >> 1) & 3)) * 8;

    auto compute = [&](int buf) {
        short8 af[MI], bfv[4];
#pragma unroll
        for (int i = 0; i < MI; ++i)
            af[i] = *(const short8*)&As[buf][(wm + i * 16 + m16) * 32 + sq];
        if constexpr (SMODE == 2) {
            // raw score -> P = exp(s - m_row); accumulate row exp-sum.
#pragma unroll
            for (int i = 0; i < MI; ++i) {
                short8 a = af[i];
#pragma unroll
                for (int e = 0; e < 8; ++e) {
                    float s  = bf2f((u16)a[e]);
                    float ev = __expf(s - mq[i]);
                    ls[i] += ev;
                    a[e] = (short)f2bf(ev);
                }
                af[i] = a;
            }
        }
#pragma unroll
        for (int j = 0; j < 4; ++j)
            bfv[j] = *(const short8*)&Bs[buf][(wn + j * 16 + m16) * 32 + sq];
#pragma unroll
        for (int i = 0; i < MI; ++i)
#pragma unroll
            for (int j = 0; j < 4; ++j)
                acc[i][j] = __builtin_amdgcn_mfma_f32_16x16x32_bf16(
                    af[i], bfv[j], acc[i][j], 0, 0, 0);
    };

    const int nt = K / 32;                       // >= 8 for all our shapes
#pragma unroll
    for (int p = 0; p < DEPTH; ++p) stage(p, p * 32);

    int cur = 0;
    for (int t = 0; t < nt - DEPTH; ++t) {
        int nxt = cur + DEPTH; if (nxt >= NBUF) nxt -= NBUF;
        stage(nxt, (t + DEPTH) * 32);            // buf consumed at t-1; safe
        wait_vmcnt<DEPTH * LPS>();               // stage(t) landed; rest fly
        barrier_fenced();
        compute(cur);
        wait_lgkm0();
        barrier_fenced();
        ++cur; if (cur == NBUF) cur = 0;
    }
    if constexpr (DEPTH == 3) {
        wait_vmcnt<2 * LPS>();
        barrier_fenced();
        compute(cur);
        wait_lgkm0();
        barrier_fenced();
        ++cur; if (cur == NBUF) cur = 0;
    }
    wait_vmcnt<LPS>();
    barrier_fenced();
    compute(cur);
    wait_lgkm0();
    barrier_fenced();
    ++cur; if (cur == NBUF) cur = 0;
    wait_vmcnt<0>();
    barrier_fenced();
    compute(cur);

    // bias into acc (C/D layout m89: col n = lane&15, row m = quad*4 + reg)
    if (bias_mode) {
#pragma unroll
        for (int i = 0; i < MI; ++i)
#pragma unroll
            for (int j = 0; j < 4; ++j)
#pragma unroll
                for (int r = 0; r < 4; ++r)
                    acc[i][j][r] += (bias_mode == 2)
                        ? bias[m0 + wm + i * 16 + quad * 4 + r]
                        : bias[n0 + wn + j * 16 + m16];
    }

    if constexpr (SMODE == 1) {
        // per-row max over this block's 128 cols -> global atomic max.
        // lane holds cols {n0+wn+j*16+m16}; 16 m16-lanes cover the row.
#pragma unroll
        for (int i = 0; i < MI; ++i)
#pragma unroll
            for (int r = 0; r < 4; ++r) {
                float mv = fmaxf(fmaxf(acc[i][0][r], acc[i][1][r]),
                                 fmaxf(acc[i][2][r], acc[i][3][r]));
#pragma unroll
                for (int off = 8; off; off >>= 1)
                    mv = fmaxf(mv, __shfl_down(mv, off, 16));
                if (m16 == 0)
                    atomicMaxF(s0g + (size_t)bz * HWc + m0 + wm + i * 16
                               + quad * 4 + r, mv);
            }
    }

    if constexpr (SMODE == 2) {
        // full-K row exp-sum: quad lanes partition K -> 2 shfl_xor hops.
#pragma unroll
        for (int i = 0; i < MI; ++i) {
            float l = ls[i];
            l += __shfl_xor(l, 16, 64);
            l += __shfl_xor(l, 32, 64);
            if (quad == 0 && w < 2) lsl[wm + i * 16 + m16] = l;
        }
        __syncthreads();
    }

    if (STORE == 0) {
        u16* C = (u16*)Cout + (size_t)bz * sC;
#pragma unroll
        for (int i = 0; i < MI; ++i) {
            int m = m0 + wm + i * 16 + quad * 4;
#pragma unroll
            for (int j = 0; j < 4; ++j) {
                int n = n0 + wn + j * 16 + m16;
#pragma unroll
                for (int r = 0; r < 4; ++r) {
                    float v = acc[i][j][r];
                    if constexpr (SMODE == 2)
                        v *= 1.0f / lsl[wm + i * 16 + quad * 4 + r];
                    C[(size_t)(m + r) * ldC + n] = f2bf(v);
                }
            }
        }
    } else {
        float* C = (float*)Cout + (size_t)bz * sC;
#pragma unroll
        for (int i = 0; i < MI; ++i) {
            int m = m0 + wm + i * 16 + quad * 4;
#pragma unroll
            for (int j = 0; j < 4; ++j) {
                int n = n0 + wn + j * 16 + m16;
#pragma unroll
                for (int r = 0; r < 4; ++r)
                    C[(size_t)(m + r) * ldC + n] = acc[i][j][r];
            }
        }
    }

    if (STATS) {
#pragma unroll
        for (int i = 0; i < MI; ++i) {
#pragma unroll
            for (int r = 0; r < 4; ++r) {
                float v0 = 0.f, v1 = 0.f;
#pragma unroll
                for (int j = 0; j < 4; ++j) {
                    float v = acc[i][j][r];
                    v0 += v;
                    v1 = fmaf(v, v, v1);
                }
#pragma unroll
                for (int off = 8; off; off >>= 1) {
                    v0 += __shfl_down(v0, off, 16);
                    v1 += __shfl_down(v1, off, 16);
                }
                if (m16 == 0) {
                    int m = m0 + wm + i * 16 + quad * 4 + r;
                    atomicAdd(&s0g[m], v0);
                    atomicAdd(&s1g[m], v1);
                }
            }
        }
    }
}

// ---------------------------------------------------------------------------
// Normalize (from raw sums) + affine + residual, float4 vectorized
// ---------------------------------------------------------------------------
__global__ __launch_bounds__(256)
void bn_apply(const float* __restrict__ wy, const float* __restrict__ x,
              const float* __restrict__ s0, const float* __restrict__ s1,
              const float* __restrict__ gamma, const float* __restrict__ beta,
              float* __restrict__ out) {
    const size_t i4 = (size_t)blockIdx.x * 256 + threadIdx.x;
    const size_t base = i4 * 4;
    const int o = (int)((base / HWc) % Cc);
    const float N = (float)(Bn * HWc);
    const float mean = s0[o] / N;
    const float var  = s1[o] / N - mean * mean;
    const float rstd = rsqrtf(var + BN_EPS);
    const float ga = gamma[o];
    const float be = beta[o];
    const float4 w4 = ((const float4*)wy)[i4];
    const float4 x4 = ((const float4*)x)[i4];
    float4 r;
    r.x = (w4.x - mean) * rstd * ga + be + x4.x;
    r.y = (w4.y - mean) * rstd * ga + be + x4.y;
    r.z = (w4.z - mean) * rstd * ga + be + x4.z;
    r.w = (w4.w - mean) * rstd * ga + be + x4.w;
    ((float4*)out)[i4] = r;
}

// ---------------------------------------------------------------------------
extern "C" void kernel_launch(void* const* d_in, const int* in_sizes, int n_in,
                              void* d_out, int out_size, void* d_ws, size_t ws_size,
                              hipStream_t stream) {
    const float* x     = (const float*)d_in[0];
    const float* g_w   = (const float*)d_in[1];
    const float* g_b   = (const float*)d_in[2];
    const float* th_w  = (const float*)d_in[3];
    const float* th_b  = (const float*)d_in[4];
    const float* ph_w  = (const float*)d_in[5];
    const float* ph_b  = (const float*)d_in[6];
    const float* w_w   = (const float*)d_in[7];
    const float* w_b   = (const float*)d_in[8];
    const float* gamma = (const float*)d_in[9];
    const float* beta  = (const float*)d_in[10];

    // Workspace aliasing (113.25 MB, unchanged):
    //  [0, 18.87M)      thph bf16 (B,HW,512)  -> later y bf16 (B,HW,IC) at [0,9.44M)
    //                   and post-S: wbf2 + stats at [9.44M, ...)
    //  [18.87M, 28.31M) g bf16 (B,IC,HW)
    //  [28.31M, 113.25M) Sreg: pre-S hosts xt + wcat + bias_thph;
    //                   S bf16 (B,HW,HW) RAW SCORES; post-PV wy fp32 (B,C,HW)
    // Row-max buffer (73.7KB) = head of d_out (scratch until bn_apply).
    char* base = (char*)d_ws;
    const size_t SZT = (size_t)Bn * HWc * ICc * 2;        // 9,437,184
    u16* thph = (u16*)base;                               // 18.87 MB
    u16* g    = (u16*)(base + 2 * SZT);                   // 9.44 MB
    char* Sreg = base + 3 * SZT;
    u16* S    = (u16*)Sreg;                               // 84.93 MB
    u16* xt   = (u16*)Sreg;                               // 18.87 MB (pre-S)
    u16* wcat = (u16*)(Sreg + (size_t)Bn * HWc * Cc * 2); // 786 KB (pre-S)
    float* bias_thph = (float*)(Sreg + (size_t)Bn * HWc * Cc * 2 + 786432);
    u16* y    = (u16*)base;                               // 9.44 MB (post-S)
    u16* wbf2 = (u16*)(base + SZT);                       // 262 KB (post-S)
    float* stats = (float*)(base + SZT + 262144);         // 4 KB (post-S)
    float* wy = (float*)Sreg;                             // 37.75 MB (post-PV)
    float* mmax = (float*)d_out;                          // 73.7 KB scratch

    dim3 blk(256);
    const u16* thphw = wcat;                   // (512,512)
    const u16* gwb   = wcat + 262144;          // (256,512)

    // init row-max buffer: 0xFF bits (NaN) valid for both atomicMaxF branches
    hipMemsetAsync(mmax, 0xFF, (size_t)Bn * HWc * sizeof(float), stream);

    cast_front<<<dim3(386), blk, 0, stream>>>(th_w, ph_w, g_w, th_b, ph_b,
                                              wcat, bias_thph);
    transpose_cast_x<<<dim3(HWc / 32, Cc / 64, Bn), blk, 0, stream>>>(x, xt);

    // thph[q][o] = sum_c xt[q][c]*thph_w[o][c] + bias  (M=2304,N=512,K=512)
    mfma_gemm<128, 0, false><<<dim3(4, 18, Bn), blk, 0, stream>>>(
        xt, thphw, thph, bias_thph, 1, Cc, Cc, Cc, 512,
        (size_t)HWc * Cc, 0, (size_t)HWc * 512, nullptr, nullptr);

    // g[ic][p] = sum_c g_w[ic][c]*xt[p][c] + g_b[ic]   (M=256,N=2304,K=512)
    mfma_gemm<64, 0, false><<<dim3(18, 4, Bn), blk, 0, stream>>>(
        gwb, xt, g, g_b, 2, Cc, Cc, Cc, HWc,
        0, (size_t)HWc * Cc, (size_t)ICc * HWc, nullptr, nullptr);

    // S = tht . pht^T RAW (M=N=2304, K=256) + fused per-row max -> mmax
    mfma_gemm<128, 0, false, 1><<<dim3(18, 18, Bn), blk, 0, stream>>>(
        thph, thph + 256, S, nullptr, 0, ICc, 512, 512, HWc,
        (size_t)HWc * 512, (size_t)HWc * 512, (size_t)HWc * HWc,
        mmax, nullptr);

    // w_w -> bf16 and zero stats (into regions dead after S-gemm)
    cast_w<<<dim3(128), blk, 0, stream>>>(w_w, wbf2);
    hipMemsetAsync(stats, 0, 2 * Cc * sizeof(float), stream);

    // y[q][ic] = sum_k exp(S[q][k]-m_q)*g[ic][k] / l_q  (softmax fused in;
    // M=2304,N=256,K=2304; replaces softmax_rows + plain PV)
    mfma_gemm<64, 0, false, 2><<<dim3(2, 36, Bn), blk, 0, stream>>>(
        S, g, y, nullptr, 0, HWc, HWc, HWc, ICc,
        (size_t)HWc * HWc, (size_t)ICc * HWc, (size_t)HWc * ICc,
        mmax, nullptr);

    // wy[o][p] = sum_ic w_w[o][ic]*y[p][ic] + w_b[o]  (M=512,N=2304,K=256)
    // fp32 out + fused BN sum/sumsq
    mfma_gemm<128, 1, true><<<dim3(18, 4, Bn), blk, 0, stream>>>(
        wbf2, y, wy, w_b, 2, ICc, ICc, ICc, HWc,
        0, (size_t)HWc * ICc, (size_t)Cc * HWc, stats, stats + Cc);

    // BatchNorm apply (stats from raw sums) + affine + residual
    // (overwrites the mmax scratch at the head of d_out)
    bn_apply<<<dim3((Bn * Cc * HWc) / 4 / 256), blk, 0, stream>>>(
        wy, x, stats, stats + Cc, gamma, beta, (float*)d_out);
}

// Round 11
// 314.029 us; speedup vs baseline: 1.0714x; 1.0714x over previous
//
#include <hip/hip_runtime.h>
#include <hip/hip_bf16.h>
#include <stdint.h>

// Problem constants (fixed by setup_inputs)
constexpr int Bn  = 8;
constexpr int Cc  = 512;
constexpr int ICc = 256;
constexpr int HWc = 48 * 48;           // 2304
constexpr float BN_EPS = 1e-5f;

typedef unsigned short u16;
typedef __attribute__((ext_vector_type(8))) short short8;   // 8 bf16 (4 VGPRs)
typedef __attribute__((ext_vector_type(4))) float f32x4;    // MFMA C/D frag

__device__ __forceinline__ u16 f2bf(float f) {
    uint32_t u = __builtin_bit_cast(uint32_t, f);
    u += 0x7fffu + ((u >> 16) & 1u);     // RNE
    return (u16)(u >> 16);
}
__device__ __forceinline__ float bf2f(u16 h) {
    uint32_t u = ((uint32_t)h) << 16;
    return __builtin_bit_cast(float, u);
}
// async global->LDS, 16B per lane; lds dst is wave-uniform base (HW adds lane*16)
__device__ __forceinline__ void load_lds16(const void* g, void* l) {
    __builtin_amdgcn_global_load_lds(
        (const __attribute__((address_space(1))) void*)(uintptr_t)g,
        (__attribute__((address_space(3))) void*)(uintptr_t)l, 16, 0, 0);
}
template <int N> __device__ __forceinline__ void wait_vmcnt() {
    if constexpr (N == 0)       asm volatile("s_waitcnt vmcnt(0)" ::: "memory");
    else if constexpr (N == 4)  asm volatile("s_waitcnt vmcnt(4)" ::: "memory");
    else if constexpr (N == 6)  asm volatile("s_waitcnt vmcnt(6)" ::: "memory");
    else if constexpr (N == 8)  asm volatile("s_waitcnt vmcnt(8)" ::: "memory");
}
__device__ __forceinline__ void wait_lgkm0() {
    asm volatile("s_waitcnt lgkmcnt(0)" ::: "memory");
}
__device__ __forceinline__ void barrier_fenced() {
    __builtin_amdgcn_s_barrier();
    asm volatile("" ::: "memory");      // keep LDS reads below the barrier
}

// ---------------------------------------------------------------------------
// Front cast: thph_w bf16 (rows 0..255=th_w, 256..511=ph_w), g_w bf16,
// bias_thph fp32 [th_b | ph_b].
// ---------------------------------------------------------------------------
__global__ __launch_bounds__(256)
void cast_front(const float* __restrict__ th_w, const float* __restrict__ ph_w,
                const float* __restrict__ g_w, const float* __restrict__ th_b,
                const float* __restrict__ ph_b, u16* __restrict__ wcat,
                float* __restrict__ bias_thph) {
    int idx = blockIdx.x * 256 + threadIdx.x;
    if (idx < 98304) {                           // ushort4 casts
        const float4* src;
        if (idx < 32768)       src = (const float4*)th_w + idx;
        else if (idx < 65536)  src = (const float4*)ph_w + (idx - 32768);
        else                   src = (const float4*)g_w  + (idx - 65536);
        float4 v = *src;
        ushort4 o;
        o.x = f2bf(v.x); o.y = f2bf(v.y); o.z = f2bf(v.z); o.w = f2bf(v.w);
        ((ushort4*)wcat)[idx] = o;
    } else if (idx < 98816) {                    // 512 bias floats
        int i = idx - 98304;
        bias_thph[i] = (i < 256) ? th_b[i] : ph_b[i - 256];
    }
}

__global__ __launch_bounds__(256)
void cast_w(const float* __restrict__ a, u16* __restrict__ out) {
    int idx = blockIdx.x * 256 + threadIdx.x;    // 0..32767
    float4 v = ((const float4*)a)[idx];
    ushort4 o;
    o.x = f2bf(v.x); o.y = f2bf(v.y); o.z = f2bf(v.z); o.w = f2bf(v.w);
    ((ushort4*)out)[idx] = o;
}

// ---------------------------------------------------------------------------
// x (B,C,HW) fp32 -> xt (B,HW,C) bf16, 64c x 32p LDS-tiled, ushort2 stores
// ---------------------------------------------------------------------------
__global__ __launch_bounds__(256)
void transpose_cast_x(const float* __restrict__ x, u16* __restrict__ xt) {
    __shared__ float t[64][33];
    const int b = blockIdx.z;
    const int p0 = blockIdx.x * 32;     // HW dir
    const int c0 = blockIdx.y * 64;     // C dir
    const int tx = threadIdx.x & 31, ty = threadIdx.x >> 5;   // ty 0..7
    const float* xb = x + (size_t)b * Cc * HWc;
#pragma unroll
    for (int r = 0; r < 8; ++r)
        t[r * 8 + ty][tx] = xb[(size_t)(c0 + r * 8 + ty) * HWc + p0 + tx];
    __syncthreads();
    u16* xtb = xt + (size_t)b * HWc * Cc;
    const int cc = (threadIdx.x & 31) * 2, pp = threadIdx.x >> 5;
#pragma unroll
    for (int r = 0; r < 4; ++r) {
        int p = r * 8 + pp;
        ushort2 v;
        v.x = f2bf(t[cc][p]);
        v.y = f2bf(t[cc + 1][p]);
        *(ushort2*)&xtb[(size_t)(p0 + p) * Cc + c0 + cc] = v;
    }
}

// ---------------------------------------------------------------------------
// bf16 MFMA GEMM: C[m][n] = sum_k A[m][k] * B[n][k] (+ bias)
//   TM=128 (BK=32): 128x128 tile, wave 2x2 (64x64); NBUF=3, depth 2.
//   TM=64  (BK=64): 64x128 tile,  wave 2x2 (32x64); NBUF=2, depth 1.
// Round-10: the TM=64 shapes are barrier-bound (72 iters x 2 barriers for
// 8 MFMA/wave each); BK=64 HALVES the iteration/barrier count with doubled
// per-iter compute, while LDS stays 48KB = 3 blocks/CU in both variants
// (round-7 lesson: the occupancy slot dominates pipeline depth).
// Counted vmcnt (T3/T4): stage(t+DEPTH) issued each iter; wait DEPTH*LPS
// drains only stage(t). Raw s_barrier + asm waits; lgkmcnt(0) before the
// tail barrier (buffer re-staged DEPTH iters later).
//
// LDS chunk-XOR swizzle (T2, rule 21: linear dest + inverse-swizzled SOURCE
// + swizzled READ). BK=32: slot q ^ ((r>>1)&3) (round-1 verified: conflicts
// 3.98M -> 0). BK=64 (8 chunks/row, 128B row stride = full bank wrap): slot
// c ^ (r&7); 16 m16-lanes -> 8 slots x 2 rows/slot = 2-way residual (free).
//
// STORE==0: bf16 C; STORE==1: fp32 C. STATS: fused per-channel(m) sum/sumsq
// via 16-lane shuffle reduce + atomicAdd. bias_mode: 0 none, 1 per-n, 2 per-m.
// ---------------------------------------------------------------------------
template <int TM, int STORE, bool STATS, int BK>
__global__ __launch_bounds__(256, 2)
void mfma_gemm(const u16* __restrict__ A, const u16* __restrict__ B,
               void* __restrict__ Cout, const float* __restrict__ bias,
               int bias_mode, int K, int ldA, int ldB, int ldC,
               size_t sA, size_t sB, size_t sC,
               float* __restrict__ s0g, float* __restrict__ s1g) {
    static_assert((TM == 128 && BK == 32) || (TM == 64 && BK == 64), "");
    constexpr int MI    = TM / 32;               // 4 (TM=128) or 2 (TM=64)
    constexpr int KSUB  = BK / 32;               // 1 or 2
    constexpr int LPS   = (TM == 128) ? 4 : 6;   // loads per wave per stage
    constexpr int NBUF  = (TM == 128) ? 3 : 2;   // 48KB LDS either way
    constexpr int DEPTH = NBUF - 1;
    __shared__ __align__(16) u16 As[NBUF][TM * BK];
    __shared__ __align__(16) u16 Bs[NBUF][128 * BK];
    const int bz = blockIdx.z;
    const int m0 = blockIdx.y * TM, n0 = blockIdx.x * 128;
    const u16* Ab = A + (size_t)bz * sA + (size_t)m0 * ldA;
    const u16* Bb = B + (size_t)bz * sB + (size_t)n0 * ldB;
    const int tid = threadIdx.x, lane = tid & 63, w = tid >> 6;
    const int wm = (w & 1) * (TM / 2);
    const int wn = (w >> 1) * 64;
    const int quad = lane >> 4, m16 = lane & 15;

    f32x4 acc[MI][4];
#pragma unroll
    for (int i = 0; i < MI; ++i)
#pragma unroll
        for (int j = 0; j < 4; ++j) acc[i][j] = (f32x4){0.f, 0.f, 0.f, 0.f};

    // BK=32 staging constants (TM=128 path)
    const int L0 = 2 * w * 64 + lane, L1 = L0 + 64;
    const int br0 = L0 >> 2, bc0 = ((L0 & 3) ^ ((L0 >> 3) & 3)) * 8;
    const int br1 = L1 >> 2, bc1 = ((L1 & 3) ^ ((L1 >> 3) & 3)) * 8;

    auto stage = [&](int buf, int k0) {
        if constexpr (BK == 32) {                // TM=128: 4 loads/wave
            load_lds16(Ab + (size_t)br0 * ldA + k0 + bc0, &As[buf][2 * w * 512]);
            load_lds16(Ab + (size_t)br1 * ldA + k0 + bc1, &As[buf][(2 * w + 1) * 512]);
            load_lds16(Bb + (size_t)br0 * ldB + k0 + bc0, &Bs[buf][2 * w * 512]);
            load_lds16(Bb + (size_t)br1 * ldB + k0 + bc1, &Bs[buf][(2 * w + 1) * 512]);
        } else {                                 // TM=64, BK=64: 2+4 loads/wave
#pragma unroll
            for (int u = 0; u < 2; ++u) {
                int L = (w * 2 + u) * 64 + lane; // 16B-unit slot
                int r = L >> 3, c = L & 7;
                load_lds16(Ab + (size_t)r * ldA + k0 + (c ^ (r & 7)) * 8,
                           &As[buf][(w * 2 + u) * 512]);
            }
#pragma unroll
            for (int u = 0; u < 4; ++u) {
                int L = (w * 4 + u) * 64 + lane;
                int r = L >> 3, c = L & 7;
                load_lds16(Bb + (size_t)r * ldB + k0 + (c ^ (r & 7)) * 8,
                           &Bs[buf][(w * 4 + u) * 512]);
            }
        }
    };

    // swizzled read offsets (u16 units) per 32-k substep
    int sqk[KSUB];
#pragma unroll
    for (int kk = 0; kk < KSUB; ++kk)
        sqk[kk] = (BK == 32) ? ((quad ^ ((m16 >> 1) & 3)) * 8)
                             : ((((kk * 4 + quad) ^ (m16 & 7))) * 8);

    auto compute = [&](int buf) {
        short8 af[MI][KSUB], bfv[4][KSUB];
#pragma unroll
        for (int i = 0; i < MI; ++i)
#pragma unroll
            for (int kk = 0; kk < KSUB; ++kk)
                af[i][kk] = *(const short8*)
                    &As[buf][(wm + i * 16 + m16) * BK + sqk[kk]];
#pragma unroll
        for (int j = 0; j < 4; ++j)
#pragma unroll
            for (int kk = 0; kk < KSUB; ++kk)
                bfv[j][kk] = *(const short8*)
                    &Bs[buf][(wn + j * 16 + m16) * BK + sqk[kk]];
#pragma unroll
        for (int kk = 0; kk < KSUB; ++kk)
#pragma unroll
            for (int i = 0; i < MI; ++i)
#pragma unroll
                for (int j = 0; j < 4; ++j)
                    acc[i][j] = __builtin_amdgcn_mfma_f32_16x16x32_bf16(
                        af[i][kk], bfv[j][kk], acc[i][j], 0, 0, 0);
    };

    const int nt = K / BK;
#pragma unroll
    for (int p = 0; p < DEPTH; ++p) stage(p, p * BK);

    int cur = 0;
    for (int t = 0; t < nt - DEPTH; ++t) {
        int nxt = cur + DEPTH; if (nxt >= NBUF) nxt -= NBUF;
        stage(nxt, (t + DEPTH) * BK);            // buf consumed at t-1; safe
        wait_vmcnt<DEPTH * LPS>();               // stage(t) landed; rest fly
        barrier_fenced();                        // ...for ALL waves
        compute(cur);
        wait_lgkm0();                            // our LDS reads done
        barrier_fenced();                        // all waves done with buf[cur]
        ++cur; if (cur == NBUF) cur = 0;
    }
    // epilogue: DEPTH stages outstanding, drain one per step
    if constexpr (DEPTH == 2) {
        wait_vmcnt<LPS>();
        barrier_fenced();
        compute(cur);
        wait_lgkm0();
        barrier_fenced();
        ++cur; if (cur == NBUF) cur = 0;
    }
    wait_vmcnt<0>();
    barrier_fenced();
    compute(cur);

    // bias into acc (C/D layout m89: col n = lane&15, row m = quad*4 + reg)
    if (bias_mode) {
#pragma unroll
        for (int i = 0; i < MI; ++i)
#pragma unroll
            for (int j = 0; j < 4; ++j)
#pragma unroll
                for (int r = 0; r < 4; ++r)
                    acc[i][j][r] += (bias_mode == 2)
                        ? bias[m0 + wm + i * 16 + quad * 4 + r]
                        : bias[n0 + wn + j * 16 + m16];
    }

    if (STORE == 0) {
        u16* C = (u16*)Cout + (size_t)bz * sC;
#pragma unroll
        for (int i = 0; i < MI; ++i) {
            int m = m0 + wm + i * 16 + quad * 4;
#pragma unroll
            for (int j = 0; j < 4; ++j) {
                int n = n0 + wn + j * 16 + m16;
#pragma unroll
                for (int r = 0; r < 4; ++r)
                    C[(size_t)(m + r) * ldC + n] = f2bf(acc[i][j][r]);
            }
        }
    } else {
        float* C = (float*)Cout + (size_t)bz * sC;
#pragma unroll
        for (int i = 0; i < MI; ++i) {
            int m = m0 + wm + i * 16 + quad * 4;
#pragma unroll
            for (int j = 0; j < 4; ++j) {
                int n = n0 + wn + j * 16 + m16;
#pragma unroll
                for (int r = 0; r < 4; ++r)
                    C[(size_t)(m + r) * ldC + n] = acc[i][j][r];
            }
        }
    }

    if (STATS) {
        // per-row partial sums over this wave's 64 n-cols, then atomic
#pragma unroll
        for (int i = 0; i < MI; ++i) {
#pragma unroll
            for (int r = 0; r < 4; ++r) {
                float v0 = 0.f, v1 = 0.f;
#pragma unroll
                for (int j = 0; j < 4; ++j) {
                    float v = acc[i][j][r];
                    v0 += v;
                    v1 = fmaf(v, v, v1);
                }
#pragma unroll
                for (int off = 8; off; off >>= 1) {
                    v0 += __shfl_down(v0, off, 16);
                    v1 += __shfl_down(v1, off, 16);
                }
                if (m16 == 0) {
                    int m = m0 + wm + i * 16 + quad * 4 + r;
                    atomicAdd(&s0g[m], v0);
                    atomicAdd(&s1g[m], v1);
                }
            }
        }
    }
}

// ---------------------------------------------------------------------------
// In-place row softmax on bf16 S (rows of 2304). 192 threads, 12 elems each.
// HBM-roofline: 170MB stream at ~6.3 TB/s ≈ 27us.
// ---------------------------------------------------------------------------
__global__ __launch_bounds__(192)
void softmax_rows(u16* __restrict__ S) {
    const int b = blockIdx.x & 7;
    const int q = blockIdx.x >> 3;
    u16* row = S + ((size_t)b * HWc + q) * (size_t)HWc;
    const int tid = threadIdx.x;

    float v[12];
#pragma unroll
    for (int c = 0; c < 3; ++c) {
        uint2 raw = *(const uint2*)&row[(c * 192 + tid) * 4];
        v[c * 4 + 0] = bf2f((u16)(raw.x & 0xffff));
        v[c * 4 + 1] = bf2f((u16)(raw.x >> 16));
        v[c * 4 + 2] = bf2f((u16)(raw.y & 0xffff));
        v[c * 4 + 3] = bf2f((u16)(raw.y >> 16));
    }
    float m = v[0];
#pragma unroll
    for (int i = 1; i < 12; ++i) m = fmaxf(m, v[i]);
#pragma unroll
    for (int off = 32; off; off >>= 1) m = fmaxf(m, __shfl_down(m, off, 64));
    __shared__ float redm[3], reds[3];
    if ((tid & 63) == 0) redm[tid >> 6] = m;
    __syncthreads();
    m = fmaxf(fmaxf(redm[0], redm[1]), redm[2]);

    float s = 0.f;
#pragma unroll
    for (int i = 0; i < 12; ++i) { v[i] = __expf(v[i] - m); s += v[i]; }
#pragma unroll
    for (int off = 32; off; off >>= 1) s += __shfl_down(s, off, 64);
    if ((tid & 63) == 0) reds[tid >> 6] = s;
    __syncthreads();
    const float rinv = 1.0f / (reds[0] + reds[1] + reds[2]);

#pragma unroll
    for (int c = 0; c < 3; ++c) {
        uint2 o;
        o.x = (uint32_t)f2bf(v[c * 4 + 0] * rinv) |
              ((uint32_t)f2bf(v[c * 4 + 1] * rinv) << 16);
        o.y = (uint32_t)f2bf(v[c * 4 + 2] * rinv) |
              ((uint32_t)f2bf(v[c * 4 + 3] * rinv) << 16);
        *(uint2*)&row[(c * 192 + tid) * 4] = o;
    }
}

// ---------------------------------------------------------------------------
// Normalize (from raw sums) + affine + residual, float4 vectorized
// ---------------------------------------------------------------------------
__global__ __launch_bounds__(256)
void bn_apply(const float* __restrict__ wy, const float* __restrict__ x,
              const float* __restrict__ s0, const float* __restrict__ s1,
              const float* __restrict__ gamma, const float* __restrict__ beta,
              float* __restrict__ out) {
    const size_t i4 = (size_t)blockIdx.x * 256 + threadIdx.x;
    const size_t base = i4 * 4;
    const int o = (int)((base / HWc) % Cc);
    const float N = (float)(Bn * HWc);
    const float mean = s0[o] / N;
    const float var  = s1[o] / N - mean * mean;
    const float rstd = rsqrtf(var + BN_EPS);
    const float ga = gamma[o];
    const float be = beta[o];
    const float4 w4 = ((const float4*)wy)[i4];
    const float4 x4 = ((const float4*)x)[i4];
    float4 r;
    r.x = (w4.x - mean) * rstd * ga + be + x4.x;
    r.y = (w4.y - mean) * rstd * ga + be + x4.y;
    r.z = (w4.z - mean) * rstd * ga + be + x4.z;
    r.w = (w4.w - mean) * rstd * ga + be + x4.w;
    ((float4*)out)[i4] = r;
}

// ---------------------------------------------------------------------------
extern "C" void kernel_launch(void* const* d_in, const int* in_sizes, int n_in,
                              void* d_out, int out_size, void* d_ws, size_t ws_size,
                              hipStream_t stream) {
    const float* x     = (const float*)d_in[0];
    const float* g_w   = (const float*)d_in[1];
    const float* g_b   = (const float*)d_in[2];
    const float* th_w  = (const float*)d_in[3];
    const float* th_b  = (const float*)d_in[4];
    const float* ph_w  = (const float*)d_in[5];
    const float* ph_b  = (const float*)d_in[6];
    const float* w_w   = (const float*)d_in[7];
    const float* w_b   = (const float*)d_in[8];
    const float* gamma = (const float*)d_in[9];
    const float* beta  = (const float*)d_in[10];

    // Workspace aliasing (113.25 MB total, same bound as previous rounds):
    //  [0, 18.87M)      thph bf16 (B,HW,512)  -> later y bf16 (B,HW,IC) at [0,9.44M)
    //                   and post-S: wbf2 + stats at [9.44M, ...)
    //  [18.87M, 28.31M) g bf16 (B,IC,HW)
    //  [28.31M, 113.25M) Sreg: pre-S hosts xt bf16 (B,HW,C) + wcat + bias_thph;
    //                   S bf16 (B,HW,HW); post-PV wy fp32 (B,C,HW)
    char* base = (char*)d_ws;
    const size_t SZT = (size_t)Bn * HWc * ICc * 2;        // 9,437,184
    u16* thph = (u16*)base;                               // 18.87 MB
    u16* g    = (u16*)(base + 2 * SZT);                   // 9.44 MB
    char* Sreg = base + 3 * SZT;
    u16* S    = (u16*)Sreg;                               // 84.93 MB
    u16* xt   = (u16*)Sreg;                               // 18.87 MB (pre-S)
    u16* wcat = (u16*)(Sreg + (size_t)Bn * HWc * Cc * 2); // 786 KB (pre-S)
    float* bias_thph = (float*)(Sreg + (size_t)Bn * HWc * Cc * 2 + 786432);
    u16* y    = (u16*)base;                               // 9.44 MB (post-S)
    u16* wbf2 = (u16*)(base + SZT);                       // 262 KB (post-S)
    float* stats = (float*)(base + SZT + 262144);         // 4 KB (post-S)
    float* wy = (float*)Sreg;                             // 37.75 MB (post-PV)

    dim3 blk(256);
    const u16* thphw = wcat;                   // (512,512)
    const u16* gwb   = wcat + 262144;          // (256,512)

    cast_front<<<dim3(386), blk, 0, stream>>>(th_w, ph_w, g_w, th_b, ph_b,
                                              wcat, bias_thph);
    transpose_cast_x<<<dim3(HWc / 32, Cc / 64, Bn), blk, 0, stream>>>(x, xt);

    // thph[q][o] = sum_c xt[q][c]*thph_w[o][c] + bias  (M=2304,N=512,K=512)
    mfma_gemm<128, 0, false, 32><<<dim3(4, 18, Bn), blk, 0, stream>>>(
        xt, thphw, thph, bias_thph, 1, Cc, Cc, Cc, 512,
        (size_t)HWc * Cc, 0, (size_t)HWc * 512, nullptr, nullptr);

    // g[ic][p] = sum_c g_w[ic][c]*xt[p][c] + g_b[ic]   (M=256,N=2304,K=512)
    mfma_gemm<64, 0, false, 64><<<dim3(18, 4, Bn), blk, 0, stream>>>(
        gwb, xt, g, g_b, 2, Cc, Cc, Cc, HWc,
        0, (size_t)HWc * Cc, (size_t)ICc * HWc, nullptr, nullptr);

    // S = tht . pht^T   (M=N=2304, K=256); tht = thph cols 0..255, pht = +256
    mfma_gemm<128, 0, false, 32><<<dim3(18, 18, Bn), blk, 0, stream>>>(
        thph, thph + 256, S, nullptr, 0, ICc, 512, 512, HWc,
        (size_t)HWc * 512, (size_t)HWc * 512, (size_t)HWc * HWc,
        nullptr, nullptr);

    // w_w -> bf16 and zero stats (into regions dead after S-gemm)
    cast_w<<<dim3(128), blk, 0, stream>>>(w_w, wbf2);
    hipMemsetAsync(stats, 0, 2 * Cc * sizeof(float), stream);

    // softmax rows, in place
    softmax_rows<<<dim3(Bn * HWc), dim3(192), 0, stream>>>(S);

    // y[q][ic] = sum_k P[q][k]*g[ic][k]  (M=2304,N=256,K=2304; BK=64: 36 iters)
    mfma_gemm<64, 0, false, 64><<<dim3(2, 36, Bn), blk, 0, stream>>>(
        S, g, y, nullptr, 0, HWc, HWc, HWc, ICc,
        (size_t)HWc * HWc, (size_t)ICc * HWc, (size_t)HWc * ICc,
        nullptr, nullptr);

    // wy[o][p] = sum_ic w_w[o][ic]*y[p][ic] + w_b[o]  (M=512,N=2304,K=256)
    // fp32 out + fused BN sum/sumsq
    mfma_gemm<128, 1, true, 32><<<dim3(18, 4, Bn), blk, 0, stream>>>(
        wbf2, y, wy, w_b, 2, ICc, ICc, ICc, HWc,
        0, (size_t)HWc * ICc, (size_t)Cc * HWc, stats, stats + Cc);

    // BatchNorm apply (stats from raw sums) + affine + residual
    bn_apply<<<dim3((Bn * Cc * HWc) / 4 / 256), blk, 0, stream>>>(
        wy, x, stats, stats + Cc, gamma, beta, (float*)d_out);
}

// Round 13
// 304.434 us; speedup vs baseline: 1.1052x; 1.0315x over previous
//
#include <hip/hip_runtime.h>
#include <hip/hip_bf16.h>
#include <stdint.h>

// Problem constants (fixed by setup_inputs)
constexpr int Bn  = 8;
constexpr int Cc  = 512;
constexpr int ICc = 256;
constexpr int HWc = 48 * 48;           // 2304
constexpr float BN_EPS = 1e-5f;

typedef unsigned short u16;
typedef __attribute__((ext_vector_type(8))) short short8;   // 8 bf16 (4 VGPRs)
typedef __attribute__((ext_vector_type(4))) float f32x4;    // MFMA C/D frag

__device__ __forceinline__ u16 f2bf(float f) {
    uint32_t u = __builtin_bit_cast(uint32_t, f);
    u += 0x7fffu + ((u >> 16) & 1u);     // RNE
    return (u16)(u >> 16);
}
__device__ __forceinline__ float bf2f(u16 h) {
    uint32_t u = ((uint32_t)h) << 16;
    return __builtin_bit_cast(float, u);
}
// async global->LDS, 16B per lane; lds dst is wave-uniform base (HW adds lane*16)
__device__ __forceinline__ void load_lds16(const void* g, void* l) {
    __builtin_amdgcn_global_load_lds(
        (const __attribute__((address_space(1))) void*)(uintptr_t)g,
        (__attribute__((address_space(3))) void*)(uintptr_t)l, 16, 0, 0);
}
template <int N> __device__ __forceinline__ void wait_vmcnt() {
    if constexpr (N == 0)       asm volatile("s_waitcnt vmcnt(0)" ::: "memory");
    else if constexpr (N == 4)  asm volatile("s_waitcnt vmcnt(4)" ::: "memory");
    else if constexpr (N == 6)  asm volatile("s_waitcnt vmcnt(6)" ::: "memory");
    else if constexpr (N == 8)  asm volatile("s_waitcnt vmcnt(8)" ::: "memory");
}
__device__ __forceinline__ void wait_lgkm0() {
    asm volatile("s_waitcnt lgkmcnt(0)" ::: "memory");
}
__device__ __forceinline__ void barrier_fenced() {
    __builtin_amdgcn_s_barrier();
    asm volatile("" ::: "memory");      // keep LDS reads below the barrier
}

// ---------------------------------------------------------------------------
// Front cast: thph_w bf16 (rows 0..255=th_w, 256..511=ph_w), g_w bf16,
// bias_thph fp32 [th_b | ph_b].
// ---------------------------------------------------------------------------
__global__ __launch_bounds__(256)
void cast_front(const float* __restrict__ th_w, const float* __restrict__ ph_w,
                const float* __restrict__ g_w, const float* __restrict__ th_b,
                const float* __restrict__ ph_b, u16* __restrict__ wcat,
                float* __restrict__ bias_thph) {
    int idx = blockIdx.x * 256 + threadIdx.x;
    if (idx < 98304) {                           // ushort4 casts
        const float4* src;
        if (idx < 32768)       src = (const float4*)th_w + idx;
        else if (idx < 65536)  src = (const float4*)ph_w + (idx - 32768);
        else                   src = (const float4*)g_w  + (idx - 65536);
        float4 v = *src;
        ushort4 o;
        o.x = f2bf(v.x); o.y = f2bf(v.y); o.z = f2bf(v.z); o.w = f2bf(v.w);
        ((ushort4*)wcat)[idx] = o;
    } else if (idx < 98816) {                    // 512 bias floats
        int i = idx - 98304;
        bias_thph[i] = (i < 256) ? th_b[i] : ph_b[i - 256];
    }
}

__global__ __launch_bounds__(256)
void cast_w(const float* __restrict__ a, u16* __restrict__ out) {
    int idx = blockIdx.x * 256 + threadIdx.x;    // 0..32767
    float4 v = ((const float4*)a)[idx];
    ushort4 o;
    o.x = f2bf(v.x); o.y = f2bf(v.y); o.z = f2bf(v.z); o.w = f2bf(v.w);
    ((ushort4*)out)[idx] = o;
}

// ---------------------------------------------------------------------------
// x (B,C,HW) fp32 -> xt (B,HW,C) bf16, 64c x 32p LDS-tiled, ushort2 stores
// ---------------------------------------------------------------------------
__global__ __launch_bounds__(256)
void transpose_cast_x(const float* __restrict__ x, u16* __restrict__ xt) {
    __shared__ float t[64][33];
    const int b = blockIdx.z;
    const int p0 = blockIdx.x * 32;     // HW dir
    const int c0 = blockIdx.y * 64;     // C dir
    const int tx = threadIdx.x & 31, ty = threadIdx.x >> 5;   // ty 0..7
    const float* xb = x + (size_t)b * Cc * HWc;
#pragma unroll
    for (int r = 0; r < 8; ++r)
        t[r * 8 + ty][tx] = xb[(size_t)(c0 + r * 8 + ty) * HWc + p0 + tx];
    __syncthreads();
    u16* xtb = xt + (size_t)b * HWc * Cc;
    const int cc = (threadIdx.x & 31) * 2, pp = threadIdx.x >> 5;
#pragma unroll
    for (int r = 0; r < 4; ++r) {
        int p = r * 8 + pp;
        ushort2 v;
        v.x = f2bf(t[cc][p]);
        v.y = f2bf(t[cc + 1][p]);
        *(ushort2*)&xtb[(size_t)(p0 + p) * Cc + c0 + cc] = v;
    }
}

// ---------------------------------------------------------------------------
// bf16 MFMA GEMM: C[m][n] = sum_k A[m][k] * B[n][k] (+ bias)
//   TM=128 (BK=32): 128x128 tile, wave 2x2 (64x64); NBUF=3, depth 2.
//   TM=64  (BK=64): 64x128 tile,  wave 2x2 (32x64); NBUF=2, depth 1.
// Round-10/11: the small-K / small-grid shapes are latency-bound (too few
// blocks/CU + too many barriers); TM=64/BK=64 doubles the grid and halves
// iterations while LDS stays 48KB = 3 blocks/CU in both variants (round-7
// lesson: the occupancy slot dominates pipeline depth). Round-11 moved the
// thph & W gemms (576 blocks @ TM=128, MfmaUtil 3.4%, Occ 12.5%) onto the
// TM=64 variant -> 1152 blocks each.
// Counted vmcnt (T3/T4): stage(t+DEPTH) issued each iter; wait DEPTH*LPS
// drains only stage(t). Raw s_barrier + asm waits; lgkmcnt(0) before the
// tail barrier (buffer re-staged DEPTH iters later).
//
// LDS chunk-XOR swizzle (T2, rule 21: linear dest + inverse-swizzled SOURCE
// + swizzled READ). BK=32: slot q ^ ((r>>1)&3) (round-1 verified: conflicts
// 3.98M -> 0). BK=64 (8 chunks/row, 128B row stride = full bank wrap): slot
// c ^ (r&7); 2-way residual (free). Round-10 verified: conflicts 0.
//
// STORE==0: bf16 C; STORE==1: fp32 C. STATS: fused per-channel(m) sum/sumsq
// via 16-lane shuffle reduce + atomicAdd. bias_mode: 0 none, 1 per-n, 2 per-m.
// ---------------------------------------------------------------------------
template <int TM, int STORE, bool STATS, int BK>
__global__ __launch_bounds__(256, 2)
void mfma_gemm(const u16* __restrict__ A, const u16* __restrict__ B,
               void* __restrict__ Cout, const float* __restrict__ bias,
               int bias_mode, int K, int ldA, int ldB, int ldC,
               size_t sA, size_t sB, size_t sC,
               float* __restrict__ s0g, float* __restrict__ s1g) {
    static_assert((TM == 128 && BK == 32) || (TM == 64 && BK == 64), "");
    constexpr int MI    = TM / 32;               // 4 (TM=128) or 2 (TM=64)
    constexpr int KSUB  = BK / 32;               // 1 or 2
    constexpr int LPS   = (TM == 128) ? 4 : 6;   // loads per wave per stage
    constexpr int NBUF  = (TM == 128) ? 3 : 2;   // 48KB LDS either way
    constexpr int DEPTH = NBUF - 1;
    __shared__ __align__(16) u16 As[NBUF][TM * BK];
    __shared__ __align__(16) u16 Bs[NBUF][128 * BK];
    const int bz = blockIdx.z;
    const int m0 = blockIdx.y * TM, n0 = blockIdx.x * 128;
    const u16* Ab = A + (size_t)bz * sA + (size_t)m0 * ldA;
    const u16* Bb = B + (size_t)bz * sB + (size_t)n0 * ldB;
    const int tid = threadIdx.x, lane = tid & 63, w = tid >> 6;
    const int wm = (w & 1) * (TM / 2);
    const int wn = (w >> 1) * 64;
    const int quad = lane >> 4, m16 = lane & 15;

    f32x4 acc[MI][4];
#pragma unroll
    for (int i = 0; i < MI; ++i)
#pragma unroll
        for (int j = 0; j < 4; ++j) acc[i][j] = (f32x4){0.f, 0.f, 0.f, 0.f};

    // BK=32 staging constants (TM=128 path)
    const int L0 = 2 * w * 64 + lane, L1 = L0 + 64;
    const int br0 = L0 >> 2, bc0 = ((L0 & 3) ^ ((L0 >> 3) & 3)) * 8;
    const int br1 = L1 >> 2, bc1 = ((L1 & 3) ^ ((L1 >> 3) & 3)) * 8;

    auto stage = [&](int buf, int k0) {
        if constexpr (BK == 32) {                // TM=128: 4 loads/wave
            load_lds16(Ab + (size_t)br0 * ldA + k0 + bc0, &As[buf][2 * w * 512]);
            load_lds16(Ab + (size_t)br1 * ldA + k0 + bc1, &As[buf][(2 * w + 1) * 512]);
            load_lds16(Bb + (size_t)br0 * ldB + k0 + bc0, &Bs[buf][2 * w * 512]);
            load_lds16(Bb + (size_t)br1 * ldB + k0 + bc1, &Bs[buf][(2 * w + 1) * 512]);
        } else {                                 // TM=64, BK=64: 2+4 loads/wave
#pragma unroll
            for (int u = 0; u < 2; ++u) {
                int L = (w * 2 + u) * 64 + lane; // 16B-unit slot
                int r = L >> 3, c = L & 7;
                load_lds16(Ab + (size_t)r * ldA + k0 + (c ^ (r & 7)) * 8,
                           &As[buf][(w * 2 + u) * 512]);
            }
#pragma unroll
            for (int u = 0; u < 4; ++u) {
                int L = (w * 4 + u) * 64 + lane;
                int r = L >> 3, c = L & 7;
                load_lds16(Bb + (size_t)r * ldB + k0 + (c ^ (r & 7)) * 8,
                           &Bs[buf][(w * 4 + u) * 512]);
            }
        }
    };

    // swizzled read offsets (u16 units) per 32-k substep
    int sqk[KSUB];
#pragma unroll
    for (int kk = 0; kk < KSUB; ++kk)
        sqk[kk] = (BK == 32) ? ((quad ^ ((m16 >> 1) & 3)) * 8)
                             : ((((kk * 4 + quad) ^ (m16 & 7))) * 8);

    auto compute = [&](int buf) {
        short8 af[MI][KSUB], bfv[4][KSUB];
#pragma unroll
        for (int i = 0; i < MI; ++i)
#pragma unroll
            for (int kk = 0; kk < KSUB; ++kk)
                af[i][kk] = *(const short8*)
                    &As[buf][(wm + i * 16 + m16) * BK + sqk[kk]];
#pragma unroll
        for (int j = 0; j < 4; ++j)
#pragma unroll
            for (int kk = 0; kk < KSUB; ++kk)
                bfv[j][kk] = *(const short8*)
                    &Bs[buf][(wn + j * 16 + m16) * BK + sqk[kk]];
#pragma unroll
        for (int kk = 0; kk < KSUB; ++kk)
#pragma unroll
            for (int i = 0; i < MI; ++i)
#pragma unroll
                for (int j = 0; j < 4; ++j)
                    acc[i][j] = __builtin_amdgcn_mfma_f32_16x16x32_bf16(
                        af[i][kk], bfv[j][kk], acc[i][j], 0, 0, 0);
    };

    const int nt = K / BK;
#pragma unroll
    for (int p = 0; p < DEPTH; ++p) stage(p, p * BK);

    int cur = 0;
    for (int t = 0; t < nt - DEPTH; ++t) {
        int nxt = cur + DEPTH; if (nxt >= NBUF) nxt -= NBUF;
        stage(nxt, (t + DEPTH) * BK);            // buf consumed at t-1; safe
        wait_vmcnt<DEPTH * LPS>();               // stage(t) landed; rest fly
        barrier_fenced();                        // ...for ALL waves
        compute(cur);
        wait_lgkm0();                            // our LDS reads done
        barrier_fenced();                        // all waves done with buf[cur]
        ++cur; if (cur == NBUF) cur = 0;
    }
    // epilogue: DEPTH stages outstanding, drain one per step
    if constexpr (DEPTH == 2) {
        wait_vmcnt<LPS>();
        barrier_fenced();
        compute(cur);
        wait_lgkm0();
        barrier_fenced();
        ++cur; if (cur == NBUF) cur = 0;
    }
    wait_vmcnt<0>();
    barrier_fenced();
    compute(cur);

    // bias into acc (C/D layout m89: col n = lane&15, row m = quad*4 + reg)
    if (bias_mode) {
#pragma unroll
        for (int i = 0; i < MI; ++i)
#pragma unroll
            for (int j = 0; j < 4; ++j)
#pragma unroll
                for (int r = 0; r < 4; ++r)
                    acc[i][j][r] += (bias_mode == 2)
                        ? bias[m0 + wm + i * 16 + quad * 4 + r]
                        : bias[n0 + wn + j * 16 + m16];
    }

    if (STORE == 0) {
        u16* C = (u16*)Cout + (size_t)bz * sC;
#pragma unroll
        for (int i = 0; i < MI; ++i) {
            int m = m0 + wm + i * 16 + quad * 4;
#pragma unroll
            for (int j = 0; j < 4; ++j) {
                int n = n0 + wn + j * 16 + m16;
#pragma unroll
                for (int r = 0; r < 4; ++r)
                    C[(size_t)(m + r) * ldC + n] = f2bf(acc[i][j][r]);
            }
        }
    } else {
        float* C = (float*)Cout + (size_t)bz * sC;
#pragma unroll
        for (int i = 0; i < MI; ++i) {
            int m = m0 + wm + i * 16 + quad * 4;
#pragma unroll
            for (int j = 0; j < 4; ++j) {
                int n = n0 + wn + j * 16 + m16;
#pragma unroll
                for (int r = 0; r < 4; ++r)
                    C[(size_t)(m + r) * ldC + n] = acc[i][j][r];
            }
        }
    }

    if (STATS) {
        // per-row partial sums over this wave's 64 n-cols, then atomic
#pragma unroll
        for (int i = 0; i < MI; ++i) {
#pragma unroll
            for (int r = 0; r < 4; ++r) {
                float v0 = 0.f, v1 = 0.f;
#pragma unroll
                for (int j = 0; j < 4; ++j) {
                    float v = acc[i][j][r];
                    v0 += v;
                    v1 = fmaf(v, v, v1);
                }
#pragma unroll
                for (int off = 8; off; off >>= 1) {
                    v0 += __shfl_down(v0, off, 16);
                    v1 += __shfl_down(v1, off, 16);
                }
                if (m16 == 0) {
                    int m = m0 + wm + i * 16 + quad * 4 + r;
                    atomicAdd(&s0g[m], v0);
                    atomicAdd(&s1g[m], v1);
                }
            }
        }
    }
}

// ---------------------------------------------------------------------------
// In-place row softmax on bf16 S (rows of 2304). 192 threads, 12 elems each.
// HBM-roofline: 170MB stream at ~6.3 TB/s ≈ 27us.
// ---------------------------------------------------------------------------
__global__ __launch_bounds__(192)
void softmax_rows(u16* __restrict__ S) {
    const int b = blockIdx.x & 7;
    const int q = blockIdx.x >> 3;
    u16* row = S + ((size_t)b * HWc + q) * (size_t)HWc;
    const int tid = threadIdx.x;

    float v[12];
#pragma unroll
    for (int c = 0; c < 3; ++c) {
        uint2 raw = *(const uint2*)&row[(c * 192 + tid) * 4];
        v[c * 4 + 0] = bf2f((u16)(raw.x & 0xffff));
        v[c * 4 + 1] = bf2f((u16)(raw.x >> 16));
        v[c * 4 + 2] = bf2f((u16)(raw.y & 0xffff));
        v[c * 4 + 3] = bf2f((u16)(raw.y >> 16));
    }
    float m = v[0];
#pragma unroll
    for (int i = 1; i < 12; ++i) m = fmaxf(m, v[i]);
#pragma unroll
    for (int off = 32; off; off >>= 1) m = fmaxf(m, __shfl_down(m, off, 64));
    __shared__ float redm[3], reds[3];
    if ((tid & 63) == 0) redm[tid >> 6] = m;
    __syncthreads();
    m = fmaxf(fmaxf(redm[0], redm[1]), redm[2]);

    float s = 0.f;
#pragma unroll
    for (int i = 0; i < 12; ++i) { v[i] = __expf(v[i] - m); s += v[i]; }
#pragma unroll
    for (int off = 32; off; off >>= 1) s += __shfl_down(s, off, 64);
    if ((tid & 63) == 0) reds[tid >> 6] = s;
    __syncthreads();
    const float rinv = 1.0f / (reds[0] + reds[1] + reds[2]);

#pragma unroll
    for (int c = 0; c < 3; ++c) {
        uint2 o;
        o.x = (uint32_t)f2bf(v[c * 4 + 0] * rinv) |
              ((uint32_t)f2bf(v[c * 4 + 1] * rinv) << 16);
        o.y = (uint32_t)f2bf(v[c * 4 + 2] * rinv) |
              ((uint32_t)f2bf(v[c * 4 + 3] * rinv) << 16);
        *(uint2*)&row[(c * 192 + tid) * 4] = o;
    }
}

// ---------------------------------------------------------------------------
// Normalize (from raw sums) + affine + residual, float4 vectorized
// ---------------------------------------------------------------------------
__global__ __launch_bounds__(256)
void bn_apply(const float* __restrict__ wy, const float* __restrict__ x,
              const float* __restrict__ s0, const float* __restrict__ s1,
              const float* __restrict__ gamma, const float* __restrict__ beta,
              float* __restrict__ out) {
    const size_t i4 = (size_t)blockIdx.x * 256 + threadIdx.x;
    const size_t base = i4 * 4;
    const int o = (int)((base / HWc) % Cc);
    const float N = (float)(Bn * HWc);
    const float mean = s0[o] / N;
    const float var  = s1[o] / N - mean * mean;
    const float rstd = rsqrtf(var + BN_EPS);
    const float ga = gamma[o];
    const float be = beta[o];
    const float4 w4 = ((const float4*)wy)[i4];
    const float4 x4 = ((const float4*)x)[i4];
    float4 r;
    r.x = (w4.x - mean) * rstd * ga + be + x4.x;
    r.y = (w4.y - mean) * rstd * ga + be + x4.y;
    r.z = (w4.z - mean) * rstd * ga + be + x4.z;
    r.w = (w4.w - mean) * rstd * ga + be + x4.w;
    ((float4*)out)[i4] = r;
}

// ---------------------------------------------------------------------------
extern "C" void kernel_launch(void* const* d_in, const int* in_sizes, int n_in,
                              void* d_out, int out_size, void* d_ws, size_t ws_size,
                              hipStream_t stream) {
    const float* x     = (const float*)d_in[0];
    const float* g_w   = (const float*)d_in[1];
    const float* g_b   = (const float*)d_in[2];
    const float* th_w  = (const float*)d_in[3];
    const float* th_b  = (const float*)d_in[4];
    const float* ph_w  = (const float*)d_in[5];
    const float* ph_b  = (const float*)d_in[6];
    const float* w_w   = (const float*)d_in[7];
    const float* w_b   = (const float*)d_in[8];
    const float* gamma = (const float*)d_in[9];
    const float* beta  = (const float*)d_in[10];

    // Workspace aliasing (113.25 MB total, same bound as previous rounds):
    //  [0, 18.87M)      thph bf16 (B,HW,512)  -> later y bf16 (B,HW,IC) at [0,9.44M)
    //                   and post-S: wbf2 + stats at [9.44M, ...)
    //  [18.87M, 28.31M) g bf16 (B,IC,HW)
    //  [28.31M, 113.25M) Sreg: pre-S hosts xt bf16 (B,HW,C) + wcat + bias_thph;
    //                   S bf16 (B,HW,HW); post-PV wy fp32 (B,C,HW)
    char* base = (char*)d_ws;
    const size_t SZT = (size_t)Bn * HWc * ICc * 2;        // 9,437,184
    u16* thph = (u16*)base;                               // 18.87 MB
    u16* g    = (u16*)(base + 2 * SZT);                   // 9.44 MB
    char* Sreg = base + 3 * SZT;
    u16* S    = (u16*)Sreg;                               // 84.93 MB
    u16* xt   = (u16*)Sreg;                               // 18.87 MB (pre-S)
    u16* wcat = (u16*)(Sreg + (size_t)Bn * HWc * Cc * 2); // 786 KB (pre-S)
    float* bias_thph = (float*)(Sreg + (size_t)Bn * HWc * Cc * 2 + 786432);
    u16* y    = (u16*)base;                               // 9.44 MB (post-S)
    u16* wbf2 = (u16*)(base + SZT);                       // 262 KB (post-S)
    float* stats = (float*)(base + SZT + 262144);         // 4 KB (post-S)
    float* wy = (float*)Sreg;                             // 37.75 MB (post-PV)

    dim3 blk(256);
    const u16* thphw = wcat;                   // (512,512)
    const u16* gwb   = wcat + 262144;          // (256,512)

    cast_front<<<dim3(386), blk, 0, stream>>>(th_w, ph_w, g_w, th_b, ph_b,
                                              wcat, bias_thph);
    transpose_cast_x<<<dim3(HWc / 32, Cc / 64, Bn), blk, 0, stream>>>(x, xt);

    // thph[q][o] = sum_c xt[q][c]*thph_w[o][c] + bias  (M=2304,N=512,K=512)
    // TM=64/BK=64 (round-11): 1152 blocks vs 576 -> latency hidden by blocks
    mfma_gemm<64, 0, false, 64><<<dim3(4, 36, Bn), blk, 0, stream>>>(
        xt, thphw, thph, bias_thph, 1, Cc, Cc, Cc, 512,
        (size_t)HWc * Cc, 0, (size_t)HWc * 512, nullptr, nullptr);

    // g[ic][p] = sum_c g_w[ic][c]*xt[p][c] + g_b[ic]   (M=256,N=2304,K=512)
    mfma_gemm<64, 0, false, 64><<<dim3(18, 4, Bn), blk, 0, stream>>>(
        gwb, xt, g, g_b, 2, Cc, Cc, Cc, HWc,
        0, (size_t)HWc * Cc, (size_t)ICc * HWc, nullptr, nullptr);

    // S = tht . pht^T   (M=N=2304, K=256); tht = thph cols 0..255, pht = +256
    // (grid 2592 = 10 blocks/CU -> block-rich; TM=128 retained)
    mfma_gemm<128, 0, false, 32><<<dim3(18, 18, Bn), blk, 0, stream>>>(
        thph, thph + 256, S, nullptr, 0, ICc, 512, 512, HWc,
        (size_t)HWc * 512, (size_t)HWc * 512, (size_t)HWc * HWc,
        nullptr, nullptr);

    // w_w -> bf16 and zero stats (into regions dead after S-gemm)
    cast_w<<<dim3(128), blk, 0, stream>>>(w_w, wbf2);
    hipMemsetAsync(stats, 0, 2 * Cc * sizeof(float), stream);

    // softmax rows, in place
    softmax_rows<<<dim3(Bn * HWc), dim3(192), 0, stream>>>(S);

    // y[q][ic] = sum_k P[q][k]*g[ic][k]  (M=2304,N=256,K=2304; BK=64: 36 iters)
    mfma_gemm<64, 0, false, 64><<<dim3(2, 36, Bn), blk, 0, stream>>>(
        S, g, y, nullptr, 0, HWc, HWc, HWc, ICc,
        (size_t)HWc * HWc, (size_t)ICc * HWc, (size_t)HWc * ICc,
        nullptr, nullptr);

    // wy[o][p] = sum_ic w_w[o][ic]*y[p][ic] + w_b[o]  (M=512,N=2304,K=256)
    // fp32 out + fused BN sum/sumsq; TM=64/BK=64 (round-11): 1152 blocks, 4 iters
    mfma_gemm<64, 1, true, 64><<<dim3(18, 8, Bn), blk, 0, stream>>>(
        wbf2, y, wy, w_b, 2, ICc, ICc, ICc, HWc,
        0, (size_t)HWc * ICc, (size_t)Cc * HWc, stats, stats + Cc);

    // BatchNorm apply (stats from raw sums) + affine + residual
    bn_apply<<<dim3((Bn * Cc * HWc) / 4 / 256), blk, 0, stream>>>(
        wy, x, stats, stats + Cc, gamma, beta, (float*)d_out);
}